// Round 6
// baseline (7594.356 us; speedup 1.0000x reference)
//
#include <hip/hip_runtime.h>
#include <hip/hip_bf16.h>

typedef _Float16 h2_t  __attribute__((ext_vector_type(2)));
typedef _Float16 f16x8 __attribute__((ext_vector_type(8)));
typedef float    f32x4 __attribute__((ext_vector_type(4)));

__device__ __forceinline__ float fdot2(h2_t a, h2_t b, float c) {
#if __has_builtin(__builtin_amdgcn_fdot2)
    return __builtin_amdgcn_fdot2(a, b, c, false);
#else
    return c + (float)a.x * (float)b.x + (float)a.y * (float)b.y;
#endif
}

__device__ __forceinline__ unsigned pack2(float lo, float hi) {
    union { h2_t h; unsigned u; } cv;
    cv.h.x = (_Float16)lo; cv.h.y = (_Float16)hi;
    return cv.u;
}

// ---------------------------------------------------------------------------
// Prep A: w2 [9*32][64] f32 -> B-fragments for mfma_f32_16x16x32_f16.
// ---------------------------------------------------------------------------
__global__ __launch_bounds__(256) void k_w2prep(
    const float* __restrict__ w2, f16x8* __restrict__ w2f)
{
    int idx = blockIdx.x * 256 + threadIdx.x;   // 9*4*64 = 2304
    if (idx >= 9 * 4 * 64) return;
    int lane = idx & 63;
    int nt   = (idx >> 6) & 3;
    int tap  = idx >> 8;
    int oc = nt * 16 + (lane & 15);
    int c0 = (lane >> 4) * 8;
    f16x8 v;
#pragma unroll
    for (int j = 0; j < 8; ++j)
        v[j] = (_Float16)w2[(tap * 32 + c0 + j) * 64 + oc];
    w2f[idx] = v;
}

// ---------------------------------------------------------------------------
// Prep B: wh [256][768] f32 -> whT [768 cols][256 k] f16 (k-contiguous).
// ---------------------------------------------------------------------------
__global__ __launch_bounds__(256) void k_whprep(
    const float* __restrict__ wh, _Float16* __restrict__ whT)
{
    int c = blockIdx.x;            // 0..767
    int k = threadIdx.x;           // 0..255
    whT[c * 256 + k] = (_Float16)wh[k * 768 + c];
}

// ---------------------------------------------------------------------------
// Fused conv1(VALU) + conv2(MFMA) + global-average-pool.  1 block = 1 frame.
// ---------------------------------------------------------------------------
__global__ __launch_bounds__(512, 4) void k_conv(
    const float* __restrict__ x,    // [512][64][64][5]
    const float* __restrict__ w1,   // [3][3][5][32]
    const float* __restrict__ b1,   // [32]
    const f16x8* __restrict__ w2f,  // [9][4][64] B-frags
    const float* __restrict__ b2,   // [64]
    float* __restrict__ pooled)     // [512][64]
{
    __shared__ _Float16 c1s[32 * 33 * 32];   // [ih][iw(+pad)][c] 67.6 KB
    __shared__ float pl[8 * 64];

    const int n = blockIdx.x;
    const int tid = threadIdx.x;
    const int lane = tid & 63, wv = tid >> 6;

    {   // zero the iw==32 pad column
        int r = tid >> 4, d = tid & 15;
        ((unsigned*)c1s)[(r * 33 + 32) * 16 + d] = 0u;
    }

    const float* xf = x + (size_t)n * 20480;

    for (int pp = 0; pp < 2; ++pp) {
        int p = tid + pp * 512;
        int oh = p >> 5, ow = p & 31;
        float acc[32];
#pragma unroll
        for (int oc = 0; oc < 32; ++oc) acc[oc] = b1[oc];
#pragma unroll
        for (int ky = 0; ky < 3; ++ky) {
            int ih = 2 * oh + ky;
            if (ih < 64) {
                const float* rb = xf + (ih * 64 + 2 * ow) * 5;
                float xv[15];
                const float2* rb2 = (const float2*)rb;
#pragma unroll
                for (int q = 0; q < 5; ++q) {
                    float2 v = rb2[q];
                    xv[2 * q] = v.x; xv[2 * q + 1] = v.y;
                }
                if (ow < 31) {
                    float2 v5 = rb2[5], v6 = rb2[6];
                    xv[10] = v5.x; xv[11] = v5.y;
                    xv[12] = v6.x; xv[13] = v6.y;
                    xv[14] = rb[14];
                } else {
                    xv[10] = xv[11] = xv[12] = xv[13] = xv[14] = 0.f;
                }
#pragma unroll
                for (int q = 0; q < 15; ++q) {
                    float v = xv[q];
                    const float* wp = w1 + (ky * 15 + q) * 32;
#pragma unroll
                    for (int oc = 0; oc < 32; ++oc)
                        acc[oc] = fmaf(v, wp[oc], acc[oc]);
                }
            }
        }
        unsigned* dst = (unsigned*)&c1s[(oh * 33 + ow) * 32];
#pragma unroll
        for (int j = 0; j < 16; ++j)
            dst[j] = pack2(fmaxf(acc[2 * j], 0.f), fmaxf(acc[2 * j + 1], 0.f));
    }
    __syncthreads();

    // conv2 as implicit GEMM via MFMA: M=256 px, N=64 oc, K=9x32
    f32x4 acc2[2][4];
#pragma unroll
    for (int mt = 0; mt < 2; ++mt)
#pragma unroll
        for (int nt = 0; nt < 4; ++nt) acc2[mt][nt] = f32x4{0.f, 0.f, 0.f, 0.f};

    const int owl = lane & 15;
    const int cb = (lane >> 4) * 8;
#pragma unroll
    for (int tap = 0; tap < 9; ++tap) {
        const int ky = tap / 3, kx = tap % 3;
        f16x8 bf[4];
#pragma unroll
        for (int nt = 0; nt < 4; ++nt)
            bf[nt] = w2f[(tap * 4 + nt) * 64 + lane];
#pragma unroll
        for (int mt = 0; mt < 2; ++mt) {
            int oh2 = wv + mt * 8;
            int ih = 2 * oh2 + ky;
            if (ih < 32) {
                int iw = 2 * owl + kx;
                f16x8 af = *(const f16x8*)&c1s[(ih * 33 + iw) * 32 + cb];
#pragma unroll
                for (int nt = 0; nt < 4; ++nt)
                    acc2[mt][nt] = __builtin_amdgcn_mfma_f32_16x16x32_f16(
                        af, bf[nt], acc2[mt][nt], 0, 0, 0);
            }
        }
    }

#pragma unroll
    for (int nt = 0; nt < 4; ++nt) {
        float b = b2[nt * 16 + owl];
        float s = 0.f;
#pragma unroll
        for (int mt = 0; mt < 2; ++mt)
#pragma unroll
            for (int r = 0; r < 4; ++r)
                s += fmaxf(acc2[mt][nt][r] + b, 0.f);
        s += __shfl_xor(s, 16, 64);
        s += __shfl_xor(s, 32, 64);
        if (lane < 16) pl[wv * 64 + nt * 16 + lane] = s;
    }
    __syncthreads();
    if (tid < 64) {
        float s = 0.f;
#pragma unroll
        for (int w = 0; w < 8; ++w) s += pl[w * 64 + tid];
        pooled[n * 64 + tid] = s * (1.0f / 256.0f);
    }
}

// ---------------------------------------------------------------------------
// Dense: feats = relu(pooled @ dw + db);  xg = feats @ wx + b_gru.
// ---------------------------------------------------------------------------
__global__ __launch_bounds__(256) void k_dense(
    const float* __restrict__ pooled,  // [512][64]
    const float* __restrict__ dw,      // [64][256]
    const float* __restrict__ db,      // [256]
    const float* __restrict__ wx,      // [256][768]
    const float* __restrict__ bg,      // [768]
    float* __restrict__ xg)            // [512][768]
{
    __shared__ float ps[4 * 64];
    __shared__ float fs[4 * 256];
    const int tid = threadIdx.x;
    const int r0 = blockIdx.x * 4;

    ps[tid & 255] = pooled[r0 * 64 + (tid & 255)];
    __syncthreads();

    {
        float a0 = db[tid], a1 = a0, a2 = a0, a3 = a0;
        for (int k = 0; k < 64; ++k) {
            float w = dw[k * 256 + tid];
            a0 = fmaf(ps[0 * 64 + k], w, a0);
            a1 = fmaf(ps[1 * 64 + k], w, a1);
            a2 = fmaf(ps[2 * 64 + k], w, a2);
            a3 = fmaf(ps[3 * 64 + k], w, a3);
        }
        fs[0 * 256 + tid] = fmaxf(a0, 0.f);
        fs[1 * 256 + tid] = fmaxf(a1, 0.f);
        fs[2 * 256 + tid] = fmaxf(a2, 0.f);
        fs[3 * 256 + tid] = fmaxf(a3, 0.f);
    }
    __syncthreads();

    float acc[3][4];
#pragma unroll
    for (int g = 0; g < 3; ++g) {
        float b = bg[g * 256 + tid];
#pragma unroll
        for (int r = 0; r < 4; ++r) acc[g][r] = b;
    }
    for (int k = 0; k < 256; ++k) {
        float f0 = fs[0 * 256 + k], f1 = fs[1 * 256 + k];
        float f2 = fs[2 * 256 + k], f3 = fs[3 * 256 + k];
#pragma unroll
        for (int g = 0; g < 3; ++g) {
            float w = wx[k * 768 + g * 256 + tid];
            acc[g][0] = fmaf(f0, w, acc[g][0]);
            acc[g][1] = fmaf(f1, w, acc[g][1]);
            acc[g][2] = fmaf(f2, w, acc[g][2]);
            acc[g][3] = fmaf(f3, w, acc[g][3]);
        }
    }
#pragma unroll
    for (int r = 0; r < 4; ++r)
#pragma unroll
        for (int g = 0; g < 3; ++g)
            xg[(size_t)(r0 + r) * 768 + g * 256 + tid] = acc[g][r];
}

// ---------------------------------------------------------------------------
// GRU scan.  16 blocks (one per batch row) x 1024 threads (16 waves).
// Thread (col, kc): col = wv*16 + (lane&15), kc = lane>>4 (4 k-chunks of 64).
// Per-thread weights: 3 gates x 32 h2 = 96 VGPRs (static indices, SROA-safe).
// Empirical law from R2-R5: the backend caps the VGPR budget at 128 no matter
// what attributes request; so the design must fit 128.  96 + ~28 working set
// fits.  waves_per_eu(4,4) pins exactly 4 waves/EU (= 1 block/CU, 128-reg
// budget) so the allocator can't target 8 waves (R4's 64-reg failure).
// Reduction over kc: shfl_xor 16 + shfl_xor 32.  2 barriers/step.
// ---------------------------------------------------------------------------
__global__ __attribute__((amdgpu_flat_work_group_size(1024, 1024),
                          amdgpu_waves_per_eu(4, 4)))
void k_gru(
    const _Float16* __restrict__ whT,  // [768 cols][256 k] f16
    const float* __restrict__ xg,      // [512][768]
    float* __restrict__ out)           // [16*32*256] seq ++ [16*256] state
{
    __shared__ float hf[256];
    __shared__ _Float16 hh[256];
    __shared__ _Float16 rhh[256];

    const int b = blockIdx.x;
    const int tid = threadIdx.x;
    const int lane = tid & 63, wv = tid >> 6;
    const int col = wv * 16 + (lane & 15);
    const int kc = lane >> 4;          // 0..3
    const int k0 = kc * 64;

    // ---- weight init: 24 k-contiguous b128 loads, even-pair extracts ----
    h2_t wz[32], wr[32], wc[32];       // 96 VGPRs, statically indexed
    {
        const f16x8* pz = (const f16x8*)(whT + (size_t)col * 256 + k0);
        const f16x8* pr = (const f16x8*)(whT + (size_t)(col + 256) * 256 + k0);
        const f16x8* pc = (const f16x8*)(whT + (size_t)(col + 512) * 256 + k0);
#pragma unroll
        for (int j = 0; j < 8; ++j) {
            f16x8 vz = pz[j], vr = pr[j], vc = pc[j];
            wz[4 * j + 0] = __builtin_shufflevector(vz, vz, 0, 1);
            wz[4 * j + 1] = __builtin_shufflevector(vz, vz, 2, 3);
            wz[4 * j + 2] = __builtin_shufflevector(vz, vz, 4, 5);
            wz[4 * j + 3] = __builtin_shufflevector(vz, vz, 6, 7);
            wr[4 * j + 0] = __builtin_shufflevector(vr, vr, 0, 1);
            wr[4 * j + 1] = __builtin_shufflevector(vr, vr, 2, 3);
            wr[4 * j + 2] = __builtin_shufflevector(vr, vr, 4, 5);
            wr[4 * j + 3] = __builtin_shufflevector(vr, vr, 6, 7);
            wc[4 * j + 0] = __builtin_shufflevector(vc, vc, 0, 1);
            wc[4 * j + 1] = __builtin_shufflevector(vc, vc, 2, 3);
            wc[4 * j + 2] = __builtin_shufflevector(vc, vc, 4, 5);
            wc[4 * j + 3] = __builtin_shufflevector(vc, vc, 6, 7);
        }
    }

    if (tid < 256) { hf[tid] = 0.f; hh[tid] = (_Float16)0.f; }
    __syncthreads();

    const f16x8* hh8 = (const f16x8*)hh;    // 32 x 16B
    const f16x8* rh8 = (const f16x8*)rhh;
    float* outb = out + (size_t)b * 32 * 256;

    const float* xrow0 = xg + (size_t)(b * 32) * 768;
    float xz = xrow0[col], xr = xrow0[col + 256], xh = xrow0[col + 512];

    for (int t = 0; t < 32; ++t) {
        const int tn = (t < 31) ? t + 1 : 31;
        const float* xnext = xg + (size_t)(b * 32 + tn) * 768;
        float nxz = xnext[col], nxr = xnext[col + 256], nxh = xnext[col + 512];

        float az0 = 0.f, az1 = 0.f, ar0 = 0.f, ar1 = 0.f;
#pragma unroll 2
        for (int j = 0; j < 8; ++j) {
            f16x8 hv = hh8[kc * 8 + j];          // 4-addr broadcast b128 read
            h2_t h0 = __builtin_shufflevector(hv, hv, 0, 1);
            h2_t h1 = __builtin_shufflevector(hv, hv, 2, 3);
            h2_t h2v = __builtin_shufflevector(hv, hv, 4, 5);
            h2_t h3 = __builtin_shufflevector(hv, hv, 6, 7);
            az0 = fdot2(wz[4 * j + 0], h0, az0);
            az1 = fdot2(wz[4 * j + 1], h1, az1);
            az0 = fdot2(wz[4 * j + 2], h2v, az0);
            az1 = fdot2(wz[4 * j + 3], h3, az1);
            ar0 = fdot2(wr[4 * j + 0], h0, ar0);
            ar1 = fdot2(wr[4 * j + 1], h1, ar1);
            ar0 = fdot2(wr[4 * j + 2], h2v, ar0);
            ar1 = fdot2(wr[4 * j + 3], h3, ar1);
        }
        float azs = az0 + az1;
        float ars = ar0 + ar1;
        azs += __shfl_xor(azs, 16, 64);
        azs += __shfl_xor(azs, 32, 64);
        ars += __shfl_xor(ars, 16, 64);
        ars += __shfl_xor(ars, 32, 64);
        float hold = hf[col];
        float z = 1.f / (1.f + __expf(-(azs + xz)));
        float r = 1.f / (1.f + __expf(-(ars + xr)));
        if (kc == 0) rhh[col] = (_Float16)(r * hold);
        __syncthreads();                          // B2: rhh visible

        float ah0 = 0.f, ah1 = 0.f;
#pragma unroll 2
        for (int j = 0; j < 8; ++j) {
            f16x8 rv = rh8[kc * 8 + j];
            h2_t r0v = __builtin_shufflevector(rv, rv, 0, 1);
            h2_t r1v = __builtin_shufflevector(rv, rv, 2, 3);
            h2_t r2v = __builtin_shufflevector(rv, rv, 4, 5);
            h2_t r3v = __builtin_shufflevector(rv, rv, 6, 7);
            ah0 = fdot2(wc[4 * j + 0], r0v, ah0);
            ah1 = fdot2(wc[4 * j + 1], r1v, ah1);
            ah0 = fdot2(wc[4 * j + 2], r2v, ah0);
            ah1 = fdot2(wc[4 * j + 3], r3v, ah1);
        }
        float ahs = ah0 + ah1;
        ahs += __shfl_xor(ahs, 16, 64);
        ahs += __shfl_xor(ahs, 32, 64);
        float sx = ahs + xh;
        sx = fminf(fmaxf(sx, -15.f), 15.f);
        float e2 = __expf(2.f * sx);
        float hc = (e2 - 1.f) / (e2 + 1.f);       // tanh
        float hn = z * hold + (1.f - z) * hc;

        if (kc == 0) {
            hf[col] = hn;
            hh[col] = (_Float16)hn;
            outb[t * 256 + col] = hn;
            if (t == 31) out[16 * 32 * 256 + b * 256 + col] = hn;
        }
        xz = nxz; xr = nxr; xh = nxh;
        __syncthreads();                          // B3: h(t) visible
    }
}

// ---------------------------------------------------------------------------
extern "C" void kernel_launch(void* const* d_in, const int* in_sizes, int n_in,
                              void* d_out, int out_size, void* d_ws,
                              size_t ws_size, hipStream_t stream)
{
    const float* x  = (const float*)d_in[0];
    const float* w1 = (const float*)d_in[1];
    const float* b1 = (const float*)d_in[2];
    const float* w2 = (const float*)d_in[3];
    const float* b2 = (const float*)d_in[4];
    const float* dw = (const float*)d_in[5];
    const float* db = (const float*)d_in[6];
    const float* wx = (const float*)d_in[7];
    const float* wh = (const float*)d_in[8];
    const float* bg = (const float*)d_in[9];
    float* out = (float*)d_out;

    float* pooled = (float*)d_ws;                  // 512*64 f32
    float* xg = pooled + 512 * 64;                 // 512*768 f32
    f16x8* w2f = (f16x8*)(xg + 512 * 768);         // 9*4*64 f16x8 (36.9 KB)
    _Float16* whT = (_Float16*)(w2f + 9 * 4 * 64); // 768*256 f16 (384 KB)

    k_w2prep<<<9, 256, 0, stream>>>(w2, w2f);
    k_whprep<<<768, 256, 0, stream>>>(wh, whT);
    k_conv<<<512, 512, 0, stream>>>(x, w1, b1, w2f, b2, pooled);
    k_dense<<<128, 256, 0, stream>>>(pooled, dw, db, wx, bg, xg);
    k_gru<<<16, 1024, 0, stream>>>(whT, xg, out);
}

// Round 7
// 153.296 us; speedup vs baseline: 49.5403x; 49.5403x over previous
//
#include <hip/hip_runtime.h>
#include <hip/hip_bf16.h>

typedef _Float16 h2_t  __attribute__((ext_vector_type(2)));
typedef _Float16 f16x8 __attribute__((ext_vector_type(8)));
typedef float    f32x4 __attribute__((ext_vector_type(4)));

__device__ __forceinline__ float fdot2(h2_t a, h2_t b, float c) {
#if __has_builtin(__builtin_amdgcn_fdot2)
    return __builtin_amdgcn_fdot2(a, b, c, false);
#else
    return c + (float)a.x * (float)b.x + (float)a.y * (float)b.y;
#endif
}

__device__ __forceinline__ unsigned pack2(float lo, float hi) {
    union { h2_t h; unsigned u; } cv;
    cv.h.x = (_Float16)lo; cv.h.y = (_Float16)hi;
    return cv.u;
}

// ---------------------------------------------------------------------------
// Prep A: w2 [9*32][64] f32 -> B-fragments for mfma_f32_16x16x32_f16.
// ---------------------------------------------------------------------------
__global__ __launch_bounds__(256) void k_w2prep(
    const float* __restrict__ w2, f16x8* __restrict__ w2f)
{
    int idx = blockIdx.x * 256 + threadIdx.x;   // 9*4*64 = 2304
    if (idx >= 9 * 4 * 64) return;
    int lane = idx & 63;
    int nt   = (idx >> 6) & 3;
    int tap  = idx >> 8;
    int oc = nt * 16 + (lane & 15);
    int c0 = (lane >> 4) * 8;
    f16x8 v;
#pragma unroll
    for (int j = 0; j < 8; ++j)
        v[j] = (_Float16)w2[(tap * 32 + c0 + j) * 64 + oc];
    w2f[idx] = v;
}

// ---------------------------------------------------------------------------
// Prep B: wh [256][768] f32 -> whT [768 cols][256 k] f16 (k-contiguous).
// ---------------------------------------------------------------------------
__global__ __launch_bounds__(256) void k_whprep(
    const float* __restrict__ wh, _Float16* __restrict__ whT)
{
    int c = blockIdx.x;            // 0..767
    int k = threadIdx.x;           // 0..255
    whT[c * 256 + k] = (_Float16)wh[k * 768 + c];
}

// ---------------------------------------------------------------------------
// Fused conv1(VALU) + conv2(MFMA) + global-average-pool.  1 block = 1 frame.
// ---------------------------------------------------------------------------
__global__ __launch_bounds__(512, 4) void k_conv(
    const float* __restrict__ x,    // [512][64][64][5]
    const float* __restrict__ w1,   // [3][3][5][32]
    const float* __restrict__ b1,   // [32]
    const f16x8* __restrict__ w2f,  // [9][4][64] B-frags
    const float* __restrict__ b2,   // [64]
    float* __restrict__ pooled)     // [512][64]
{
    __shared__ _Float16 c1s[32 * 33 * 32];   // [ih][iw(+pad)][c] 67.6 KB
    __shared__ float pl[8 * 64];

    const int n = blockIdx.x;
    const int tid = threadIdx.x;
    const int lane = tid & 63, wv = tid >> 6;

    {   // zero the iw==32 pad column
        int r = tid >> 4, d = tid & 15;
        ((unsigned*)c1s)[(r * 33 + 32) * 16 + d] = 0u;
    }

    const float* xf = x + (size_t)n * 20480;

    for (int pp = 0; pp < 2; ++pp) {
        int p = tid + pp * 512;
        int oh = p >> 5, ow = p & 31;
        float acc[32];
#pragma unroll
        for (int oc = 0; oc < 32; ++oc) acc[oc] = b1[oc];
#pragma unroll
        for (int ky = 0; ky < 3; ++ky) {
            int ih = 2 * oh + ky;
            if (ih < 64) {
                const float* rb = xf + (ih * 64 + 2 * ow) * 5;
                float xv[15];
                const float2* rb2 = (const float2*)rb;
#pragma unroll
                for (int q = 0; q < 5; ++q) {
                    float2 v = rb2[q];
                    xv[2 * q] = v.x; xv[2 * q + 1] = v.y;
                }
                if (ow < 31) {
                    float2 v5 = rb2[5], v6 = rb2[6];
                    xv[10] = v5.x; xv[11] = v5.y;
                    xv[12] = v6.x; xv[13] = v6.y;
                    xv[14] = rb[14];
                } else {
                    xv[10] = xv[11] = xv[12] = xv[13] = xv[14] = 0.f;
                }
#pragma unroll
                for (int q = 0; q < 15; ++q) {
                    float v = xv[q];
                    const float* wp = w1 + (ky * 15 + q) * 32;
#pragma unroll
                    for (int oc = 0; oc < 32; ++oc)
                        acc[oc] = fmaf(v, wp[oc], acc[oc]);
                }
            }
        }
        unsigned* dst = (unsigned*)&c1s[(oh * 33 + ow) * 32];
#pragma unroll
        for (int j = 0; j < 16; ++j)
            dst[j] = pack2(fmaxf(acc[2 * j], 0.f), fmaxf(acc[2 * j + 1], 0.f));
    }
    __syncthreads();

    // conv2 as implicit GEMM via MFMA: M=256 px, N=64 oc, K=9x32
    f32x4 acc2[2][4];
#pragma unroll
    for (int mt = 0; mt < 2; ++mt)
#pragma unroll
        for (int nt = 0; nt < 4; ++nt) acc2[mt][nt] = f32x4{0.f, 0.f, 0.f, 0.f};

    const int owl = lane & 15;
    const int cb = (lane >> 4) * 8;
#pragma unroll
    for (int tap = 0; tap < 9; ++tap) {
        const int ky = tap / 3, kx = tap % 3;
        f16x8 bf[4];
#pragma unroll
        for (int nt = 0; nt < 4; ++nt)
            bf[nt] = w2f[(tap * 4 + nt) * 64 + lane];
#pragma unroll
        for (int mt = 0; mt < 2; ++mt) {
            int oh2 = wv + mt * 8;
            int ih = 2 * oh2 + ky;
            if (ih < 32) {
                int iw = 2 * owl + kx;
                f16x8 af = *(const f16x8*)&c1s[(ih * 33 + iw) * 32 + cb];
#pragma unroll
                for (int nt = 0; nt < 4; ++nt)
                    acc2[mt][nt] = __builtin_amdgcn_mfma_f32_16x16x32_f16(
                        af, bf[nt], acc2[mt][nt], 0, 0, 0);
            }
        }
    }

#pragma unroll
    for (int nt = 0; nt < 4; ++nt) {
        float b = b2[nt * 16 + owl];
        float s = 0.f;
#pragma unroll
        for (int mt = 0; mt < 2; ++mt)
#pragma unroll
            for (int r = 0; r < 4; ++r)
                s += fmaxf(acc2[mt][nt][r] + b, 0.f);
        s += __shfl_xor(s, 16, 64);
        s += __shfl_xor(s, 32, 64);
        if (lane < 16) pl[wv * 64 + nt * 16 + lane] = s;
    }
    __syncthreads();
    if (tid < 64) {
        float s = 0.f;
#pragma unroll
        for (int w = 0; w < 8; ++w) s += pl[w * 64 + tid];
        pooled[n * 64 + tid] = s * (1.0f / 256.0f);
    }
}

// ---------------------------------------------------------------------------
// Dense: feats = relu(pooled @ dw + db);  xg = feats @ wx + b_gru.
// ---------------------------------------------------------------------------
__global__ __launch_bounds__(256) void k_dense(
    const float* __restrict__ pooled,  // [512][64]
    const float* __restrict__ dw,      // [64][256]
    const float* __restrict__ db,      // [256]
    const float* __restrict__ wx,      // [256][768]
    const float* __restrict__ bg,      // [768]
    float* __restrict__ xg)            // [512][768]
{
    __shared__ float ps[4 * 64];
    __shared__ float fs[4 * 256];
    const int tid = threadIdx.x;
    const int r0 = blockIdx.x * 4;

    ps[tid & 255] = pooled[r0 * 64 + (tid & 255)];
    __syncthreads();

    {
        float a0 = db[tid], a1 = a0, a2 = a0, a3 = a0;
        for (int k = 0; k < 64; ++k) {
            float w = dw[k * 256 + tid];
            a0 = fmaf(ps[0 * 64 + k], w, a0);
            a1 = fmaf(ps[1 * 64 + k], w, a1);
            a2 = fmaf(ps[2 * 64 + k], w, a2);
            a3 = fmaf(ps[3 * 64 + k], w, a3);
        }
        fs[0 * 256 + tid] = fmaxf(a0, 0.f);
        fs[1 * 256 + tid] = fmaxf(a1, 0.f);
        fs[2 * 256 + tid] = fmaxf(a2, 0.f);
        fs[3 * 256 + tid] = fmaxf(a3, 0.f);
    }
    __syncthreads();

    float acc[3][4];
#pragma unroll
    for (int g = 0; g < 3; ++g) {
        float b = bg[g * 256 + tid];
#pragma unroll
        for (int r = 0; r < 4; ++r) acc[g][r] = b;
    }
    for (int k = 0; k < 256; ++k) {
        float f0 = fs[0 * 256 + k], f1 = fs[1 * 256 + k];
        float f2 = fs[2 * 256 + k], f3 = fs[3 * 256 + k];
#pragma unroll
        for (int g = 0; g < 3; ++g) {
            float w = wx[k * 768 + g * 256 + tid];
            acc[g][0] = fmaf(f0, w, acc[g][0]);
            acc[g][1] = fmaf(f1, w, acc[g][1]);
            acc[g][2] = fmaf(f2, w, acc[g][2]);
            acc[g][3] = fmaf(f3, w, acc[g][3]);
        }
    }
#pragma unroll
    for (int r = 0; r < 4; ++r)
#pragma unroll
        for (int g = 0; g < 3; ++g)
            xg[(size_t)(r0 + r) * 768 + g * 256 + tid] = acc[g][r];
}

// ---------------------------------------------------------------------------
// GRU scan with weights PINNED IN AGPRS via inline asm.
// R2-R6 lesson: the allocator caps arch VGPRs at ~116 and spills any large
// weight array.  gfx950 has a unified 512-reg VGPR+AGPR file and this kernel
// uses no MFMA, so a0..a191 are free real estate the allocator can't touch.
// 16 blocks x 512 threads; col = wv*32+(lane&31); kc = lane>>5 (k-half).
// Per-thread: 192 h2 weights in a0..a191 (z: a0-63, r: a64-127, c: a128-191).
// arch-VGPR working set < 64 -> 256 total/wave -> 2 waves/SIMD, 1 block/CU.
// ---------------------------------------------------------------------------
union H2I { h2_t h; int i; };

#define SV2(v, i) __builtin_shufflevector((v), (v), 2*(i), 2*(i)+1)

#define AWR(N, val) asm volatile("v_accvgpr_write_b32 a" #N ", %0" \
                                 :: "v"(val) : "a" #N)
#define ARD(N, dst) asm volatile("v_accvgpr_read_b32 %0, a" #N : "=v"(dst))

#define LW(P, JJ, N0, N1, N2, N3) do {                                  \
    f16x8 v_ = (P)[JJ];                                                 \
    H2I t0_, t1_, t2_, t3_;                                             \
    t0_.h = SV2(v_, 0); t1_.h = SV2(v_, 1);                             \
    t2_.h = SV2(v_, 2); t3_.h = SV2(v_, 3);                             \
    AWR(N0, t0_.i); AWR(N1, t1_.i); AWR(N2, t2_.i); AWR(N3, t3_.i);     \
} while (0)

#define RDZR(JJ, Z0, Z1, Z2, Z3, R0, R1, R2, R3) do {                   \
    f16x8 hv_ = hh8[kc * 16 + JJ];                                      \
    H2I w0_, w1_, w2_, w3_, w4_, w5_, w6_, w7_;                         \
    ARD(Z0, w0_.i); ARD(Z1, w1_.i); ARD(Z2, w2_.i); ARD(Z3, w3_.i);     \
    ARD(R0, w4_.i); ARD(R1, w5_.i); ARD(R2, w6_.i); ARD(R3, w7_.i);     \
    h2_t h0_ = SV2(hv_, 0), h1_ = SV2(hv_, 1);                          \
    h2_t h2_ = SV2(hv_, 2), h3_ = SV2(hv_, 3);                          \
    az0 = fdot2(w0_.h, h0_, az0); az1 = fdot2(w1_.h, h1_, az1);         \
    az0 = fdot2(w2_.h, h2_, az0); az1 = fdot2(w3_.h, h3_, az1);         \
    ar0 = fdot2(w4_.h, h0_, ar0); ar1 = fdot2(w5_.h, h1_, ar1);         \
    ar0 = fdot2(w6_.h, h2_, ar0); ar1 = fdot2(w7_.h, h3_, ar1);         \
} while (0)

#define RDC(JJ, C0, C1, C2, C3) do {                                    \
    f16x8 rv_ = rh8[kc * 16 + JJ];                                      \
    H2I w0_, w1_, w2_, w3_;                                             \
    ARD(C0, w0_.i); ARD(C1, w1_.i); ARD(C2, w2_.i); ARD(C3, w3_.i);     \
    h2_t h0_ = SV2(rv_, 0), h1_ = SV2(rv_, 1);                          \
    h2_t h2_ = SV2(rv_, 2), h3_ = SV2(rv_, 3);                          \
    ah0 = fdot2(w0_.h, h0_, ah0); ah1 = fdot2(w1_.h, h1_, ah1);         \
    ah0 = fdot2(w2_.h, h2_, ah0); ah1 = fdot2(w3_.h, h3_, ah1);         \
} while (0)

#define SBAR() __builtin_amdgcn_sched_barrier(0)

__global__ __attribute__((amdgpu_flat_work_group_size(512, 512)))
void k_gru(
    const _Float16* __restrict__ whT,  // [768 cols][256 k] f16
    const float* __restrict__ xg,      // [512][768]
    float* __restrict__ out)           // [16*32*256] seq ++ [16*256] state
{
    __shared__ float hf[256];
    __shared__ _Float16 hh[256];
    __shared__ _Float16 rhh[256];

    const int b = blockIdx.x;
    const int tid = threadIdx.x;
    const int lane = tid & 63, wv = tid >> 6;
    const int col = wv * 32 + (lane & 31);
    const int kc = lane >> 5;          // 0 or 1
    const int k0 = kc * 128;

    // ---- pin weights into a0..a191 (8 loads per group, barriers between) ---
    {
        const f16x8* pz = (const f16x8*)(whT + (size_t)col * 256 + k0);
        const f16x8* pr = (const f16x8*)(whT + (size_t)(col + 256) * 256 + k0);
        const f16x8* pc = (const f16x8*)(whT + (size_t)(col + 512) * 256 + k0);

        LW(pz, 0, 0, 1, 2, 3);     LW(pz, 1, 4, 5, 6, 7);
        LW(pz, 2, 8, 9, 10, 11);   LW(pz, 3, 12, 13, 14, 15);
        LW(pz, 4, 16, 17, 18, 19); LW(pz, 5, 20, 21, 22, 23);
        LW(pz, 6, 24, 25, 26, 27); LW(pz, 7, 28, 29, 30, 31);
        SBAR();
        LW(pz, 8, 32, 33, 34, 35);  LW(pz, 9, 36, 37, 38, 39);
        LW(pz, 10, 40, 41, 42, 43); LW(pz, 11, 44, 45, 46, 47);
        LW(pz, 12, 48, 49, 50, 51); LW(pz, 13, 52, 53, 54, 55);
        LW(pz, 14, 56, 57, 58, 59); LW(pz, 15, 60, 61, 62, 63);
        SBAR();
        LW(pr, 0, 64, 65, 66, 67);  LW(pr, 1, 68, 69, 70, 71);
        LW(pr, 2, 72, 73, 74, 75);  LW(pr, 3, 76, 77, 78, 79);
        LW(pr, 4, 80, 81, 82, 83);  LW(pr, 5, 84, 85, 86, 87);
        LW(pr, 6, 88, 89, 90, 91);  LW(pr, 7, 92, 93, 94, 95);
        SBAR();
        LW(pr, 8, 96, 97, 98, 99);     LW(pr, 9, 100, 101, 102, 103);
        LW(pr, 10, 104, 105, 106, 107); LW(pr, 11, 108, 109, 110, 111);
        LW(pr, 12, 112, 113, 114, 115); LW(pr, 13, 116, 117, 118, 119);
        LW(pr, 14, 120, 121, 122, 123); LW(pr, 15, 124, 125, 126, 127);
        SBAR();
        LW(pc, 0, 128, 129, 130, 131);  LW(pc, 1, 132, 133, 134, 135);
        LW(pc, 2, 136, 137, 138, 139);  LW(pc, 3, 140, 141, 142, 143);
        LW(pc, 4, 144, 145, 146, 147);  LW(pc, 5, 148, 149, 150, 151);
        LW(pc, 6, 152, 153, 154, 155);  LW(pc, 7, 156, 157, 158, 159);
        SBAR();
        LW(pc, 8, 160, 161, 162, 163);  LW(pc, 9, 164, 165, 166, 167);
        LW(pc, 10, 168, 169, 170, 171); LW(pc, 11, 172, 173, 174, 175);
        LW(pc, 12, 176, 177, 178, 179); LW(pc, 13, 180, 181, 182, 183);
        LW(pc, 14, 184, 185, 186, 187); LW(pc, 15, 188, 189, 190, 191);
        SBAR();
    }

    if (tid < 256) { hf[tid] = 0.f; hh[tid] = (_Float16)0.f; }
    __syncthreads();

    const f16x8* hh8 = (const f16x8*)hh;    // 32 x 16B
    const f16x8* rh8 = (const f16x8*)rhh;
    float* outb = out + (size_t)b * 32 * 256;

    const float* xrow0 = xg + (size_t)(b * 32) * 768;
    float xz = xrow0[col], xr = xrow0[col + 256], xh = xrow0[col + 512];

    for (int t = 0; t < 32; ++t) {
        const int tn = (t < 31) ? t + 1 : 31;
        const float* xnext = xg + (size_t)(b * 32 + tn) * 768;
        float nxz = xnext[col], nxr = xnext[col + 256], nxh = xnext[col + 512];

        float az0 = 0.f, az1 = 0.f, ar0 = 0.f, ar1 = 0.f;
        RDZR(0, 0, 1, 2, 3, 64, 65, 66, 67);
        RDZR(1, 4, 5, 6, 7, 68, 69, 70, 71);
        RDZR(2, 8, 9, 10, 11, 72, 73, 74, 75);
        RDZR(3, 12, 13, 14, 15, 76, 77, 78, 79);
        SBAR();
        RDZR(4, 16, 17, 18, 19, 80, 81, 82, 83);
        RDZR(5, 20, 21, 22, 23, 84, 85, 86, 87);
        RDZR(6, 24, 25, 26, 27, 88, 89, 90, 91);
        RDZR(7, 28, 29, 30, 31, 92, 93, 94, 95);
        SBAR();
        RDZR(8, 32, 33, 34, 35, 96, 97, 98, 99);
        RDZR(9, 36, 37, 38, 39, 100, 101, 102, 103);
        RDZR(10, 40, 41, 42, 43, 104, 105, 106, 107);
        RDZR(11, 44, 45, 46, 47, 108, 109, 110, 111);
        SBAR();
        RDZR(12, 48, 49, 50, 51, 112, 113, 114, 115);
        RDZR(13, 52, 53, 54, 55, 116, 117, 118, 119);
        RDZR(14, 56, 57, 58, 59, 120, 121, 122, 123);
        RDZR(15, 60, 61, 62, 63, 124, 125, 126, 127);
        SBAR();

        float azs = az0 + az1;
        float ars = ar0 + ar1;
        azs += __shfl_xor(azs, 32, 64);
        ars += __shfl_xor(ars, 32, 64);
        float hold = hf[col];
        float z = 1.f / (1.f + __expf(-(azs + xz)));
        float r = 1.f / (1.f + __expf(-(ars + xr)));
        if (kc == 0) rhh[col] = (_Float16)(r * hold);
        __syncthreads();                          // B2: rhh visible

        float ah0 = 0.f, ah1 = 0.f;
        RDC(0, 128, 129, 130, 131);
        RDC(1, 132, 133, 134, 135);
        RDC(2, 136, 137, 138, 139);
        RDC(3, 140, 141, 142, 143);
        SBAR();
        RDC(4, 144, 145, 146, 147);
        RDC(5, 148, 149, 150, 151);
        RDC(6, 152, 153, 154, 155);
        RDC(7, 156, 157, 158, 159);
        SBAR();
        RDC(8, 160, 161, 162, 163);
        RDC(9, 164, 165, 166, 167);
        RDC(10, 168, 169, 170, 171);
        RDC(11, 172, 173, 174, 175);
        SBAR();
        RDC(12, 176, 177, 178, 179);
        RDC(13, 180, 181, 182, 183);
        RDC(14, 184, 185, 186, 187);
        RDC(15, 188, 189, 190, 191);
        SBAR();

        float ahs = ah0 + ah1;
        ahs += __shfl_xor(ahs, 32, 64);
        float sx = ahs + xh;
        sx = fminf(fmaxf(sx, -15.f), 15.f);
        float e2 = __expf(2.f * sx);
        float hc = (e2 - 1.f) / (e2 + 1.f);       // tanh
        float hn = z * hold + (1.f - z) * hc;

        if (kc == 0) {
            hf[col] = hn;
            hh[col] = (_Float16)hn;
            outb[t * 256 + col] = hn;
            if (t == 31) out[16 * 32 * 256 + b * 256 + col] = hn;
        }
        xz = nxz; xr = nxr; xh = nxh;
        __syncthreads();                          // B3: h(t) visible
    }
}

// ---------------------------------------------------------------------------
extern "C" void kernel_launch(void* const* d_in, const int* in_sizes, int n_in,
                              void* d_out, int out_size, void* d_ws,
                              size_t ws_size, hipStream_t stream)
{
    const float* x  = (const float*)d_in[0];
    const float* w1 = (const float*)d_in[1];
    const float* b1 = (const float*)d_in[2];
    const float* w2 = (const float*)d_in[3];
    const float* b2 = (const float*)d_in[4];
    const float* dw = (const float*)d_in[5];
    const float* db = (const float*)d_in[6];
    const float* wx = (const float*)d_in[7];
    const float* wh = (const float*)d_in[8];
    const float* bg = (const float*)d_in[9];
    float* out = (float*)d_out;

    float* pooled = (float*)d_ws;                  // 512*64 f32
    float* xg = pooled + 512 * 64;                 // 512*768 f32
    f16x8* w2f = (f16x8*)(xg + 512 * 768);         // 9*4*64 f16x8 (36.9 KB)
    _Float16* whT = (_Float16*)(w2f + 9 * 4 * 64); // 768*256 f16 (384 KB)

    k_w2prep<<<9, 256, 0, stream>>>(w2, w2f);
    k_whprep<<<768, 256, 0, stream>>>(wh, whT);
    k_conv<<<512, 512, 0, stream>>>(x, w1, b1, w2f, b2, pooled);
    k_dense<<<128, 256, 0, stream>>>(pooled, dw, db, wx, bg, xg);
    k_gru<<<16, 512, 0, stream>>>(whT, xg, out);
}